// Round 2
// baseline (773.450 us; speedup 1.0000x reference)
//
#include <hip/hip_runtime.h>
#include <hip/hip_bf16.h>

// ---------------------------------------------------------------------------
// HRAInjectedLinear: out = x @ (W * prod_i (I - 2 u_i u_i^T))^T
//   K1 gram_raw : Graw = hu^T hu (8x8, raw columns; norms = sqrt(diag))
//   K2 fused_wn : per W-row: y = row·U (block reduce), v-recurrence,
//                 Wn_row = bf16(row - 2 sum_j v_j u_j^T). W read ONCE.
//   K3 cast_x   : Xb = bf16(x)
//   K4 gemm_bt  : out = Xb @ Wn^T, bf16 MFMA 128x128 tile, m97 structure
//                 + XOR-swizzled LDS staging (kills 8-way bank conflicts)
// ---------------------------------------------------------------------------

#define D_IN   4096
#define D_OUT  4096
#define R_HH   8
#define M_ROWS 8192   // B*S = 4*2048

typedef short bf16x8 __attribute__((ext_vector_type(8)));
typedef float f32x4  __attribute__((ext_vector_type(4)));

__device__ inline unsigned short f2bf(float f) {
    unsigned int x = __float_as_uint(f);
    unsigned int lsb = (x >> 16) & 1u;
    x += 0x7fffu + lsb;                 // round-to-nearest-even
    return (unsigned short)(x >> 16);
}

__device__ inline void async16(const unsigned short* g, short* l) {
    __builtin_amdgcn_global_load_lds(
        (const __attribute__((address_space(1))) void*)g,
        (__attribute__((address_space(3))) void*)l,
        16, 0, 0);
}

// --- K1: raw Gram matrix Graw[i][j] = hu[:,i]·hu[:,j] ----------------------
__global__ void gram_raw(const float* __restrict__ hu, float* __restrict__ G) {
    const int i = blockIdx.x >> 3, j = blockIdx.x & 7;
    float s = 0.f;
    for (int k = threadIdx.x; k < D_IN; k += 256)
        s += hu[k * R_HH + i] * hu[k * R_HH + j];
    __shared__ float red[256];
    red[threadIdx.x] = s;
    __syncthreads();
    for (int off = 128; off > 0; off >>= 1) {
        if (threadIdx.x < off) red[threadIdx.x] += red[threadIdx.x + off];
        __syncthreads();
    }
    if (threadIdx.x == 0) G[i * R_HH + j] = red[0];
}

// --- K2: fused per-row Householder update + bf16 cast ----------------------
// row o: t_j = sum_k w_k hu[k][j]; y_j = invn_j t_j;
//        v_i = y_i - 2 sum_{j<i} (Graw[j][i] invn_j invn_i) v_j;
//        Wn[o][k] = bf16(w_k - sum_j (2 v_j invn_j) hu[k][j])
__global__ __launch_bounds__(256) void fused_wn(
    const float* __restrict__ W, const float* __restrict__ hu,
    const float* __restrict__ Graw, unsigned short* __restrict__ Wn) {
    const int o = blockIdx.x;
    __shared__ float sG[64];
    if (threadIdx.x < 64) sG[threadIdx.x] = Graw[threadIdx.x];
    __syncthreads();
    float invn[8];
    #pragma unroll
    for (int j = 0; j < 8; j++) invn[j] = rsqrtf(sG[j * 8 + j]);

    const float4* wrow4 = (const float4*)(W + (size_t)o * D_IN);
    float4 wreg[4];
    float t[8] = {0, 0, 0, 0, 0, 0, 0, 0};
    #pragma unroll
    for (int i = 0; i < 4; i++) {
        const int k4 = threadIdx.x + i * 256;
        float4 wv = wrow4[k4];
        wreg[i] = wv;
        float wa[4] = {wv.x, wv.y, wv.z, wv.w};
        #pragma unroll
        for (int e = 0; e < 4; e++) {
            const int k = k4 * 4 + e;
            const float4* u4 = (const float4*)&hu[k * R_HH];
            float4 a = u4[0], b = u4[1];
            t[0] += wa[e] * a.x; t[1] += wa[e] * a.y;
            t[2] += wa[e] * a.z; t[3] += wa[e] * a.w;
            t[4] += wa[e] * b.x; t[5] += wa[e] * b.y;
            t[6] += wa[e] * b.z; t[7] += wa[e] * b.w;
        }
    }
    __shared__ float red[8 * 256];
    #pragma unroll
    for (int j = 0; j < 8; j++) red[j * 256 + threadIdx.x] = t[j];
    __syncthreads();
    for (int off = 128; off > 0; off >>= 1) {
        if (threadIdx.x < off)
            #pragma unroll
            for (int j = 0; j < 8; j++)
                red[j * 256 + threadIdx.x] += red[j * 256 + threadIdx.x + off];
        __syncthreads();
    }
    float y[8], v[8], s[8];
    #pragma unroll
    for (int j = 0; j < 8; j++) y[j] = red[j * 256] * invn[j];
    #pragma unroll
    for (int i = 0; i < 8; i++) {
        float tv = y[i];
        #pragma unroll
        for (int j = 0; j < 8; j++)
            if (j < i) tv -= 2.0f * (sG[j * 8 + i] * invn[j] * invn[i]) * v[j];
        v[i] = tv;
    }
    #pragma unroll
    for (int j = 0; j < 8; j++) s[j] = 2.0f * v[j] * invn[j];

    ushort4* outrow = (ushort4*)(Wn + (size_t)o * D_IN);
    #pragma unroll
    for (int i = 0; i < 4; i++) {
        const int k4 = threadIdx.x + i * 256;
        float wa[4] = {wreg[i].x, wreg[i].y, wreg[i].z, wreg[i].w};
        float ov[4];
        #pragma unroll
        for (int e = 0; e < 4; e++) {
            const int k = k4 * 4 + e;
            const float4* u4 = (const float4*)&hu[k * R_HH];
            float4 a = u4[0], b = u4[1];
            float c = s[0]*a.x + s[1]*a.y + s[2]*a.z + s[3]*a.w
                    + s[4]*b.x + s[5]*b.y + s[6]*b.z + s[7]*b.w;
            ov[e] = wa[e] - c;
        }
        ushort4 r;
        r.x = f2bf(ov[0]); r.y = f2bf(ov[1]); r.z = f2bf(ov[2]); r.w = f2bf(ov[3]);
        outrow[k4] = r;
    }
}

// --- K3: Xb = bf16(x) ------------------------------------------------------
__global__ void cast_x(const float4* __restrict__ x, ushort4* __restrict__ xb, int n4) {
    const int g = blockIdx.x * 256 + threadIdx.x;
    if (g >= n4) return;
    float4 f = x[g];
    ushort4 r;
    r.x = f2bf(f.x); r.y = f2bf(f.y); r.z = f2bf(f.z); r.w = f2bf(f.w);
    xb[g] = r;
}

// --- K4: C = A B^T, bf16 MFMA, 128x128 tile, XOR-swizzled LDS --------------
// LDS slot (row, c) holds global element (row, c ^ swz(row)),
// swz(row) = ((row>>1)&3)*8 shorts (16B units). Reader bank-group index =
// (4*(row&1) + (quad ^ ((row>>1)&3))) mod 8 -> 2 lanes/group = conflict-free.
__global__ __launch_bounds__(256) void gemm_bt(
    const unsigned short* __restrict__ A,   // [M][K] bf16 bits
    const unsigned short* __restrict__ B,   // [N][K] bf16 bits
    float* __restrict__ C) {                // [M][N]
    constexpr int K = D_IN, N = D_OUT;
    __shared__ __align__(16) short sA[128 * 32];
    __shared__ __align__(16) short sB[128 * 32];
    const int tid  = threadIdx.x;
    const int lane = tid & 63;
    const int wave = tid >> 6;
    const int wr = (wave >> 1) * 64;
    const int wc = (wave & 1) * 64;
    const size_t bm = (size_t)blockIdx.y * 128;
    const size_t bn = (size_t)blockIdx.x * 128;

    const unsigned short* Ab = A + bm * K;
    const unsigned short* Bb = B + bn * K;
    const int r0 = tid >> 2;                           // staging row, pass 0
    const int kg = (((tid & 3) ^ ((tid >> 3) & 3)) * 8); // swizzled global k-off
    const size_t ga0 = (size_t)r0 * K + kg;            // swz(r0+64)==swz(r0)
    const size_t ga1 = (size_t)(r0 + 64) * K + kg;

    f32x4 acc[4][4];
    #pragma unroll
    for (int i = 0; i < 4; i++)
        #pragma unroll
        for (int j = 0; j < 4; j++)
            acc[i][j] = (f32x4){0.f, 0.f, 0.f, 0.f};

    const int arow = wr + (lane & 15);
    const int brow = wc + (lane & 15);
    const int koff = (lane >> 4) * 8;
    const int swA = ((arow >> 1) & 3) * 8;   // row+16 preserves (row>>1)&3
    const int swB = ((brow >> 1) & 3) * 8;
    const int kA = koff ^ swA;
    const int kB = koff ^ swB;

    for (int k0 = 0; k0 < K; k0 += 32) {
        __syncthreads();                    // LDS free (prev compute done)
        async16(Ab + ga0 + k0, &sA[tid * 8]);
        async16(Ab + ga1 + k0, &sA[2048 + tid * 8]);
        async16(Bb + ga0 + k0, &sB[tid * 8]);
        async16(Bb + ga1 + k0, &sB[2048 + tid * 8]);
        __syncthreads();                    // vmcnt(0)+barrier: tiles ready

        bf16x8 a[4], b[4];
        #pragma unroll
        for (int i = 0; i < 4; i++)
            a[i] = *(const bf16x8*)&sA[(arow + i * 16) * 32 + kA];
        #pragma unroll
        for (int j = 0; j < 4; j++)
            b[j] = *(const bf16x8*)&sB[(brow + j * 16) * 32 + kB];
        #pragma unroll
        for (int i = 0; i < 4; i++)
            #pragma unroll
            for (int j = 0; j < 4; j++)
                acc[i][j] = __builtin_amdgcn_mfma_f32_16x16x32_bf16(
                    a[i], b[j], acc[i][j], 0, 0, 0);
    }

    // epilogue: C/D layout col=lane&15, row=(lane>>4)*4+reg  [m89-verified]
    const int crow0 = (lane >> 4) * 4;
    const int ccol  = lane & 15;
    #pragma unroll
    for (int i = 0; i < 4; i++) {
        #pragma unroll
        for (int j = 0; j < 4; j++) {
            size_t base = (bm + wr + i * 16 + crow0) * (size_t)N
                        + (bn + wc + j * 16 + ccol);
            #pragma unroll
            for (int r = 0; r < 4; r++)
                C[base + (size_t)r * N] = acc[i][j][r];
        }
    }
}

// ---------------------------------------------------------------------------
extern "C" void kernel_launch(void* const* d_in, const int* in_sizes, int n_in,
                              void* d_out, int out_size, void* d_ws, size_t ws_size,
                              hipStream_t stream) {
    const float* x      = (const float*)d_in[0];   // [4,2048,4096]
    const float* weight = (const float*)d_in[1];   // [4096,4096]
    const float* hra_u  = (const float*)d_in[2];   // [4096,8]
    float* out = (float*)d_out;                    // [4,2048,4096]

    // workspace layout (all 16B aligned)
    char* w = (char*)d_ws;
    unsigned short* Xb = (unsigned short*)w;                              // 64 MB
    unsigned short* Wn = (unsigned short*)(w + (size_t)64 * 1024 * 1024); // 32 MB
    float* Graw = (float*)(w + (size_t)96 * 1024 * 1024);                 // 256 B

    gram_raw<<<R_HH * R_HH, 256, 0, stream>>>(hra_u, Graw);
    fused_wn<<<D_OUT, 256, 0, stream>>>(weight, hra_u, Graw, Wn);

    const int n4 = M_ROWS * D_IN / 4;
    cast_x<<<(n4 + 255) / 256, 256, 0, stream>>>((const float4*)x, (ushort4*)Xb, n4);

    dim3 grid(D_OUT / 128, M_ROWS / 128);
    gemm_bt<<<grid, 256, 0, stream>>>(Xb, Wn, out);
}